// Round 6
// baseline (604.598 us; speedup 1.0000x reference)
//
#include <hip/hip_runtime.h>

#define BB 8
#define HH 512
#define WW 512
#define K2 9
#define HW (HH * WW)

// Tile geometry: each 256-thread block computes a TY x TX pixel tile,
// 4 x-consecutive pixels per thread. LDS stages depth rows/cols with a
// 5-wide halo (covers |offset|<=4; N(0,1) tail -> inline global patch).
#define TX 64
#define TY 16
#define NROWS (TY + 11)    // 27
#define NCOLS (TX + 11)    // 75
#define STRIDE (NCOLS + 1) // 76 words; 76%32=12 -> breaks pow2 banking

__global__ __launch_bounds__(256, 8) void pp_deconv_kernel(
    const float* __restrict__ depth,   // (B,1,H,W)
    const float* __restrict__ weight,  // (B,K2,H,W)
    const float* __restrict__ offset,  // (B,2*K2,H,W)
    float* __restrict__ out)           // (B,1,H,W)
{
    __shared__ float tile[NROWS * STRIDE];

    const int tid = threadIdx.x;
    const int tx0 = blockIdx.x * TX;
    const int ty0 = blockIdx.y * TY;
    const int b   = blockIdx.z;

    const int ry0 = ty0 - 5;   // global row of tile row 0
    const int cx0 = tx0 - 5;   // global col of tile col 0

    const float* dimg = depth + (size_t)b * HW;

    // ---- stage depth tile + halo; zero outside image (== reference mask) ----
    for (int li = tid; li < NROWS * NCOLS; li += 256) {
        const int r = li / NCOLS;
        const int c = li - r * NCOLS;
        const int gy = ry0 + r;
        const int gx = cx0 + c;
        float v = 0.f;
        if ((unsigned)gy < HH && (unsigned)gx < WW) v = dimg[gy * WW + gx];
        tile[r * STRIDE + c] = v;
    }
    __syncthreads();

    // ---- 4 x-consecutive pixels per thread ----
    const int xl = (tid & 15) << 2;   // 0..60
    const int yl = tid >> 4;          // 0..15
    const int x = tx0 + xl;
    const int y = ty0 + yl;
    const int p = y * WW + x;

    const float* wp = weight + (size_t)b * K2 * HW + p;
    const float* op = offset + (size_t)b * 2 * K2 * HW + p;

    float4 accw = make_float4(0.f, 0.f, 0.f, 0.f);
    float4 accs = make_float4(0.f, 0.f, 0.f, 0.f);
    float4 wsum = make_float4(0.f, 0.f, 0.f, 0.f);

#pragma unroll
    for (int k = 0; k < K2; ++k) {
        const int ky = k / 3;
        const int kx = k % 3;
        const float4 w4  = *(const float4*)(wp + k * HW);
        const float4 dy4 = *(const float4*)(op + (2 * k) * HW);
        const float4 dx4 = *(const float4*)(op + (2 * k + 1) * HW);

        const float ybase = (float)(y - 1 + ky);
        const float xbase = (float)(x - 1 + kx);

        float s[4];
        const float pys[4] = {dy4.x + ybase, dy4.y + ybase,
                              dy4.z + ybase, dy4.w + ybase};
        const float pxs[4] = {dx4.x + xbase, dx4.y + xbase + 1.f,
                              dx4.z + xbase + 2.f, dx4.w + xbase + 3.f};
#pragma unroll
        for (int j = 0; j < 4; ++j) {
            const float py = pys[j], px = pxs[j];
            const float y0f = floorf(py);
            const float x0f = floorf(px);
            const float ty = py - y0f;
            const float tx = px - x0f;
            const int iy = (int)y0f - ry0;   // tile row of top corner
            const int ix = (int)x0f - cx0;   // tile col of left corner

            // clamped tile coords -> always-safe LDS reads (common path)
            const int iyc = min(max(iy, 0), NROWS - 2);
            const int ixc = min(max(ix, 0), NCOLS - 2);
            const float* q = tile + iyc * STRIDE + ixc;
            float v00 = q[0], v01 = q[1];
            float v10 = q[STRIDE], v11 = q[STRIDE + 1];

            const bool intile = ((unsigned)iy < NROWS - 1) &
                                ((unsigned)ix < NCOLS - 1);
            if (!intile) {
                // Rare: patch corners from global (clamp load, mask invalid).
                const int y0 = iy + ry0, x0 = ix + cx0;
                const int y1 = y0 + 1,  x1 = x0 + 1;
                const int y0c = min(max(y0, 0), HH - 1);
                const int y1c = min(max(y1, 0), HH - 1);
                const int x0c = min(max(x0, 0), WW - 1);
                const int x1c = min(max(x1, 0), WW - 1);
                const float g00 = dimg[y0c * WW + x0c];
                const float g01 = dimg[y0c * WW + x1c];
                const float g10 = dimg[y1c * WW + x0c];
                const float g11 = dimg[y1c * WW + x1c];
                const bool vy0 = (unsigned)y0 < HH, vy1 = (unsigned)y1 < HH;
                const bool vx0 = (unsigned)x0 < WW, vx1 = (unsigned)x1 < WW;
                v00 = (vy0 & vx0) ? g00 : 0.f;
                v01 = (vy0 & vx1) ? g01 : 0.f;
                v10 = (vy1 & vx0) ? g10 : 0.f;
                v11 = (vy1 & vx1) ? g11 : 0.f;
            }
            // zeros (staged or masked) encode the reference's validity mask
            const float a0 = v00 + tx * (v01 - v00);
            const float a1 = v10 + tx * (v11 - v10);
            s[j] = a0 + ty * (a1 - a0);
        }
        accw.x += s[0] * w4.x;  accs.x += s[0];  wsum.x += w4.x;
        accw.y += s[1] * w4.y;  accs.y += s[1];  wsum.y += w4.y;
        accw.z += s[2] * w4.z;  accs.z += s[2];  wsum.z += w4.z;
        accw.w += s[3] * w4.w;  accs.w += s[3];  wsum.w += w4.w;
    }

    // residual depth from LDS (always in-tile, in-image)
    const float* dq = tile + (yl + 5) * STRIDE + (xl + 5);
    const float c9 = 1.0f / 9.0f;
    float4 o;
    o.x = accw.x - wsum.x * c9 * accs.x + dq[0];
    o.y = accw.y - wsum.y * c9 * accs.y + dq[1];
    o.z = accw.z - wsum.z * c9 * accs.z + dq[2];
    o.w = accw.w - wsum.w * c9 * accs.w + dq[3];
    *(float4*)(out + (size_t)b * HW + p) = o;
}

extern "C" void kernel_launch(void* const* d_in, const int* in_sizes, int n_in,
                              void* d_out, int out_size, void* d_ws, size_t ws_size,
                              hipStream_t stream) {
    const float* depth  = (const float*)d_in[0];
    const float* weight = (const float*)d_in[1];
    const float* offset = (const float*)d_in[2];
    float* out = (float*)d_out;

    dim3 grid(WW / TX, HH / TY, BB);   // 8 x 32 x 8 = 2048 blocks (8/CU)
    dim3 block(256);
    pp_deconv_kernel<<<grid, block, 0, stream>>>(depth, weight, offset, out);
}

// Round 7
// 489.452 us; speedup vs baseline: 1.2353x; 1.2353x over previous
//
#include <hip/hip_runtime.h>

#define BB 8
#define HH 512
#define WW 512
#define K2 9
#define HW (HH * WW)

// Tile geometry: each 256-thread block computes a TY x TX pixel tile,
// 4 x-consecutive pixels per thread. LDS stages depth rows/cols with a
// 5-wide halo (covers |offset|<=4; N(0,1) tail -> inline global patch).
// NOTE: launch_bounds(256,8) forced 32 VGPRs -> 870 MB scratch spill, 434 us
// (round 6). (256,4) gives the allocator 128 regs; spill-free matters more
// than the extra occupancy here.
#define TX 64
#define TY 16
#define NROWS (TY + 11)    // 27
#define NCOLS (TX + 11)    // 75
#define STRIDE (NCOLS + 1) // 76 words; 76%32=12 -> breaks pow2 banking

__global__ __launch_bounds__(256, 4) void pp_deconv_kernel(
    const float* __restrict__ depth,   // (B,1,H,W)
    const float* __restrict__ weight,  // (B,K2,H,W)
    const float* __restrict__ offset,  // (B,2*K2,H,W)
    float* __restrict__ out)           // (B,1,H,W)
{
    __shared__ float tile[NROWS * STRIDE];

    const int tid = threadIdx.x;
    const int tx0 = blockIdx.x * TX;
    const int ty0 = blockIdx.y * TY;
    const int b   = blockIdx.z;

    const int ry0 = ty0 - 5;   // global row of tile row 0
    const int cx0 = tx0 - 5;   // global col of tile col 0

    const float* dimg = depth + (size_t)b * HW;

    // ---- stage depth tile + halo; zero outside image (== reference mask) ----
    for (int li = tid; li < NROWS * NCOLS; li += 256) {
        const int r = li / NCOLS;
        const int c = li - r * NCOLS;
        const int gy = ry0 + r;
        const int gx = cx0 + c;
        float v = 0.f;
        if ((unsigned)gy < HH && (unsigned)gx < WW) v = dimg[gy * WW + gx];
        tile[r * STRIDE + c] = v;
    }
    __syncthreads();

    // ---- 4 x-consecutive pixels per thread ----
    const int xl = (tid & 15) << 2;   // 0..60
    const int yl = tid >> 4;          // 0..15
    const int x = tx0 + xl;
    const int y = ty0 + yl;
    const int p = y * WW + x;

    const float* wp = weight + (size_t)b * K2 * HW + p;
    const float* op = offset + (size_t)b * 2 * K2 * HW + p;

    float4 accw = make_float4(0.f, 0.f, 0.f, 0.f);
    float4 accs = make_float4(0.f, 0.f, 0.f, 0.f);
    float4 wsum = make_float4(0.f, 0.f, 0.f, 0.f);

#pragma unroll
    for (int k = 0; k < K2; ++k) {
        const int ky = k / 3;
        const int kx = k % 3;
        const float4 w4  = *(const float4*)(wp + k * HW);
        const float4 dy4 = *(const float4*)(op + (2 * k) * HW);
        const float4 dx4 = *(const float4*)(op + (2 * k + 1) * HW);

        const float ybase = (float)(y - 1 + ky);
        const float xbase = (float)(x - 1 + kx);

        float s[4];
        const float pys[4] = {dy4.x + ybase, dy4.y + ybase,
                              dy4.z + ybase, dy4.w + ybase};
        const float pxs[4] = {dx4.x + xbase, dx4.y + xbase + 1.f,
                              dx4.z + xbase + 2.f, dx4.w + xbase + 3.f};
#pragma unroll
        for (int j = 0; j < 4; ++j) {
            const float py = pys[j], px = pxs[j];
            const float y0f = floorf(py);
            const float x0f = floorf(px);
            const float ty = py - y0f;
            const float tx = px - x0f;
            const int iy = (int)y0f - ry0;   // tile row of top corner
            const int ix = (int)x0f - cx0;   // tile col of left corner

            // clamped tile coords -> always-safe LDS reads (common path)
            const int iyc = min(max(iy, 0), NROWS - 2);
            const int ixc = min(max(ix, 0), NCOLS - 2);
            const float* q = tile + iyc * STRIDE + ixc;
            float v00 = q[0], v01 = q[1];
            float v10 = q[STRIDE], v11 = q[STRIDE + 1];

            const bool intile = ((unsigned)iy < NROWS - 1) &
                                ((unsigned)ix < NCOLS - 1);
            if (!intile) {
                // Rare: patch corners from global (clamp load, mask invalid).
                const int y0 = iy + ry0, x0 = ix + cx0;
                const int y1 = y0 + 1,  x1 = x0 + 1;
                const int y0c = min(max(y0, 0), HH - 1);
                const int y1c = min(max(y1, 0), HH - 1);
                const int x0c = min(max(x0, 0), WW - 1);
                const int x1c = min(max(x1, 0), WW - 1);
                const float g00 = dimg[y0c * WW + x0c];
                const float g01 = dimg[y0c * WW + x1c];
                const float g10 = dimg[y1c * WW + x0c];
                const float g11 = dimg[y1c * WW + x1c];
                const bool vy0 = (unsigned)y0 < HH, vy1 = (unsigned)y1 < HH;
                const bool vx0 = (unsigned)x0 < WW, vx1 = (unsigned)x1 < WW;
                v00 = (vy0 & vx0) ? g00 : 0.f;
                v01 = (vy0 & vx1) ? g01 : 0.f;
                v10 = (vy1 & vx0) ? g10 : 0.f;
                v11 = (vy1 & vx1) ? g11 : 0.f;
            }
            // zeros (staged or masked) encode the reference's validity mask
            const float a0 = v00 + tx * (v01 - v00);
            const float a1 = v10 + tx * (v11 - v10);
            s[j] = a0 + ty * (a1 - a0);
        }
        accw.x += s[0] * w4.x;  accs.x += s[0];  wsum.x += w4.x;
        accw.y += s[1] * w4.y;  accs.y += s[1];  wsum.y += w4.y;
        accw.z += s[2] * w4.z;  accs.z += s[2];  wsum.z += w4.z;
        accw.w += s[3] * w4.w;  accs.w += s[3];  wsum.w += w4.w;
    }

    // residual depth from LDS (always in-tile, in-image)
    const float* dq = tile + (yl + 5) * STRIDE + (xl + 5);
    const float c9 = 1.0f / 9.0f;
    float4 o;
    o.x = accw.x - wsum.x * c9 * accs.x + dq[0];
    o.y = accw.y - wsum.y * c9 * accs.y + dq[1];
    o.z = accw.z - wsum.z * c9 * accs.z + dq[2];
    o.w = accw.w - wsum.w * c9 * accs.w + dq[3];
    *(float4*)(out + (size_t)b * HW + p) = o;
}

extern "C" void kernel_launch(void* const* d_in, const int* in_sizes, int n_in,
                              void* d_out, int out_size, void* d_ws, size_t ws_size,
                              hipStream_t stream) {
    const float* depth  = (const float*)d_in[0];
    const float* weight = (const float*)d_in[1];
    const float* offset = (const float*)d_in[2];
    float* out = (float*)d_out;

    dim3 grid(WW / TX, HH / TY, BB);   // 8 x 32 x 8 = 2048 blocks
    dim3 block(256);
    pp_deconv_kernel<<<grid, block, 0, stream>>>(depth, weight, offset, out);
}